// Round 11
// baseline (288.691 us; speedup 1.0000x reference)
//
#include <hip/hip_runtime.h>
#include <hip/hip_bf16.h>

#define CHUNK 16    // edges per thread in scan kernels; block covers 4096
#define EPB  8192   // edges per k_bin block
#define TPB_BIN 1024
#define BROWS 128   // rank-rows per bucket
#define BCAP 16384  // entry capacity per bucket (early buckets size-biased to ~8300
                    // mean; 8192 overflowed (r5/r6); 16384 ≈ 15σ)

typedef __attribute__((ext_vector_type(8))) short bhalf8;
typedef __attribute__((ext_vector_type(4))) float floatx4;

__device__ __forceinline__ unsigned short f2bf(float f) {
    __hip_bfloat16 h = __float2bfloat16(f);     // native RNE; compiler emits v_cvt_pk
    union { __hip_bfloat16 h; unsigned short u; } v;
    v.h = h;
    return v.u;
}

// ---------------- init: pos = E; cursorb[b] = b*BCAP ----------------
__global__ void k_init(int* __restrict__ pos, int* __restrict__ cursorb, int N, int nbuck, int E) {
    int i = blockIdx.x * blockDim.x + threadIdx.x;
    if (i < N) pos[i] = E;
    if (i < nbuck) cursorb[i] = i * BCAP;
}

// ---------------- prep: W1T/W2T bf16 transposed weights ----------------
__global__ void k_prep(const float* __restrict__ W1, const float* __restrict__ W2,
                       unsigned short* __restrict__ W1T, unsigned short* __restrict__ W2T) {
    int i = blockIdx.x * blockDim.x + threadIdx.x;
    if (i < 256 * 256) {
        int c = i >> 8, k = i & 255;
        W1T[i] = f2bf(W1[k * 256 + c]);     // W1T[c][k] = W1[k][c]
    }
    if (i < 48 * 320) {
        int c = i / 320, k = i % 320;
        W2T[i] = (c < 40) ? f2bf(W2[k * 40 + c]) : (unsigned short)0;
    }
}

// ---------------- pos[n] = min edge index with seg==n (read-filtered atomic, proven) ----------------
__global__ void k_posmin(const int* __restrict__ ei, int* __restrict__ pos, int E) {
    int e = blockIdx.x * blockDim.x + threadIdx.x;
    if (e < E) {
        int s = ((const int2*)ei)[e].x;
        if (pos[s] > e) atomicMin(&pos[s], e);
    }
}

// ---------------- per-block flag counts (proven) ----------------
__global__ void k_flagsum(const int* __restrict__ ei, const int* __restrict__ pos,
                          int* __restrict__ bsum, int E) {
    __shared__ int sdata[256];
    int t = threadIdx.x;
    int base = (blockIdx.x * 256 + t) * CHUNK;
    int cnt = 0;
    for (int l = 0; l < CHUNK; l++) {
        int e = base + l;
        if (e < E) {
            int s = ((const int2*)ei)[e].x;
            if (pos[s] == e) cnt++;
        }
    }
    sdata[t] = cnt;
    __syncthreads();
    for (int s = 128; s > 0; s >>= 1) {
        if (t < s) sdata[t] += sdata[t + s];
        __syncthreads();
    }
    if (t == 0) bsum[blockIdx.x] = sdata[0];
}

// ---------------- exclusive scan of block sums (proven) ----------------
__global__ void k_scanbsum(int* __restrict__ bsum, int nblk) {
    __shared__ int part[1024];
    const int T = 1024;
    int t = threadIdx.x;
    int per = (nblk + T - 1) / T;
    int s0 = t * per, s1 = min(s0 + per, nblk);
    int sum = 0;
    for (int i = s0; i < s1; i++) sum += bsum[i];
    part[t] = sum;
    __syncthreads();
    for (int off = 1; off < T; off <<= 1) {
        int v = 0;
        if (t >= off) v = part[t - off];
        __syncthreads();
        part[t] += v;
        __syncthreads();
    }
    int run = part[t] - sum;
    for (int i = s0; i < s1; i++) {
        int old = bsum[i];
        bsum[i] = run;
        run += old;
    }
    if (t == T - 1) bsum[nblk] = part[T - 1];
}

// ---------------- rank write at flagged positions (proven) ----------------
__global__ void k_prefix_rank(const int* __restrict__ ei, const int* __restrict__ pos,
                              const int* __restrict__ bsum, int* __restrict__ rank, int E) {
    __shared__ int sdata[256];
    int t = threadIdx.x;
    int base = (blockIdx.x * 256 + t) * CHUNK;
    int cnt = 0;
    for (int l = 0; l < CHUNK; l++) {
        int e = base + l;
        if (e < E) {
            int s = ((const int2*)ei)[e].x;
            if (pos[s] == e) cnt++;
        }
    }
    sdata[t] = cnt;
    __syncthreads();
    for (int off = 1; off < 256; off <<= 1) {
        int v = 0;
        if (t >= off) v = sdata[t - off];
        __syncthreads();
        sdata[t] += v;
        __syncthreads();
    }
    int run = bsum[blockIdx.x] + sdata[t] - cnt;
    for (int l = 0; l < CHUNK; l++) {
        int e = base + l;
        if (e >= E) break;
        int s = ((const int2*)ei)[e].x;
        if (pos[s] == e) { rank[s] = run; run++; }
    }
}

// ---------------- bin edges into coarse buckets: 1024 thr, LDS-staged m/pv (proven) ----------------
__global__ __launch_bounds__(TPB_BIN) void k_bin(const int* __restrict__ ei, const int* __restrict__ rank,
                                                 const int* __restrict__ ef, int* __restrict__ cursorb,
                                                 unsigned* __restrict__ binned, int E, int nbuck) {
    __shared__ int lme[EPB];              // 32KB: destination rank per staged edge
    __shared__ unsigned short lpv[EPB];   // 16KB: packed 4x4-bit features
    __shared__ int lcnt[800];
    __shared__ int lbase[800];
    __shared__ int lfill[800];
    int tid = threadIdx.x;
    int base = blockIdx.x * EPB;
    for (int b = tid; b < nbuck; b += TPB_BIN) { lcnt[b] = 0; lfill[b] = 0; }
    __syncthreads();
    // pass 1: gather + stage + count
#pragma unroll
    for (int j = 0; j < EPB / TPB_BIN; j++) {
        int li = j * TPB_BIN + tid;
        int idx = base + li;
        if (idx < E) {
            int s = ((const int2*)ei)[idx].x;       // seg[e]
            int t = ((const int2*)ei)[s].x;         // seg[seg[e]], s < N <= E
            int m = rank[t];
            int4 f = *reinterpret_cast<const int4*>(ef + 4 * (size_t)idx);
            lme[li] = m;
            lpv[li] = (unsigned short)(f.x | (f.y << 4) | (f.z << 8) | (f.w << 12));
            atomicAdd(&lcnt[m >> 7], 1);
        } else {
            lme[li] = -1;
        }
    }
    __syncthreads();
    // claim contiguous global runs per bucket
    for (int b = tid; b < nbuck; b += TPB_BIN) {
        int c = lcnt[b];
        lbase[b] = (c > 0) ? atomicAdd(&cursorb[b], c) : 0;
    }
    __syncthreads();
    // pass 2: write from LDS only
#pragma unroll
    for (int j = 0; j < EPB / TPB_BIN; j++) {
        int li = j * TPB_BIN + tid;
        int m = lme[li];
        if (m >= 0) {
            int b = m >> 7;
            int off = atomicAdd(&lfill[b], 1);
            long long slot = (long long)lbase[b] + off;
            if (slot < (long long)(b + 1) * BCAP)   // overflow guard
                binned[slot] = ((unsigned)(m & (BROWS - 1)) << 16) | lpv[li];
        }
    }
}

// ---------------- bucket gather: LDS histogram -> u16 agg rows (proven) ----------------
__global__ __launch_bounds__(256) void k_bgather(const int* __restrict__ cursorb,
                                                 const unsigned* __restrict__ binned,
                                                 unsigned short* __restrict__ agg, int N) {
    __shared__ int hist[BROWS * 64];   // 32KB
    int tid = threadIdx.x;
    int b = blockIdx.x;
    int m0 = b * BROWS;
    for (int i = tid; i < BROWS * 64; i += 256) hist[i] = 0;
    __syncthreads();
    int r0 = b * BCAP;
    int r1 = min(cursorb[b], (b + 1) * BCAP);   // clamp: never read beyond bucket region
    for (int i = r0 + tid; i < r1; i += 256) {
        unsigned v = binned[i];
        int lr = (int)(v >> 16) << 6;           // local row (m&127) * 64
        atomicAdd(&hist[lr + (v & 15u)], 1);
        atomicAdd(&hist[lr + 16 + ((v >> 4) & 15u)], 1);
        atomicAdd(&hist[lr + 32 + ((v >> 8) & 15u)], 1);
        atomicAdd(&hist[lr + 48 + ((v >> 12) & 15u)], 1);
    }
    __syncthreads();
    int rows = min(BROWS, N - m0);
    for (int i = tid; i < rows * 64; i += 256)
        agg[(size_t)m0 * 64 + i] = (unsigned short)hist[i];
}

// ---------------- fused MFMA: out = [relu(x@W1+b1) | agg] @ W2 + b2 ----------------
// 512 threads / 8 waves / 64-row tile. __launch_bounds__(512,4): 4 waves/EU target
// -> VGPR budget 128 (round-10's default targeted 8/EU -> 40 VGPR -> serial latency
// chains). Fragment loads software-pipelined 2-deep; stage loads issued up front.
__global__ __launch_bounds__(512, 4) void k_fused(const float* __restrict__ x,
                                               const unsigned short* __restrict__ W1T,
                                               const float* __restrict__ b1,
                                               const unsigned short* __restrict__ W2T,
                                               const float* __restrict__ b2,
                                               const unsigned short* __restrict__ agg,
                                               float* __restrict__ out, int N) {
    __shared__ __align__(16) unsigned short xs[64 * 256];  // x tile bf16, then z tile bf16
    __shared__ __align__(16) unsigned short as[64 * 64];   // agg tile bf16
    int tid = threadIdx.x;
    int lane = tid & 63;
    int w = tid >> 6;                       // 0..7
    int lrow = lane & 15, lkb = lane >> 4;
    int n0 = blockIdx.x * 64;

    // ---- stage: issue ALL global loads first, then cvt+LDS-write ----
    {
        int limit = (N - n0) * 64;                       // valid float4 count
        const float4* xp = reinterpret_cast<const float4*>(x + (size_t)n0 * 256);
        float4 xv[8];
#pragma unroll
        for (int j = 0; j < 8; j++) {
            int f = j * 512 + tid;
            xv[j] = (f < limit) ? xp[f] : make_float4(0.f, 0.f, 0.f, 0.f);
        }
        int limita = (N - n0) * 16;                      // valid ushort4 count
        const ushort4* ap = reinterpret_cast<const ushort4*>(agg + (size_t)n0 * 64);
        ushort4 av[2];
#pragma unroll
        for (int j = 0; j < 2; j++) {
            int f = j * 512 + tid;
            av[j] = (f < limita) ? ap[f] : make_ushort4(0, 0, 0, 0);
        }
#pragma unroll
        for (int j = 0; j < 8; j++) {
            int f = j * 512 + tid;
            int row = f >> 6, c4 = (f & 63) * 4;
            ushort4 bv;
            bv.x = f2bf(xv[j].x); bv.y = f2bf(xv[j].y); bv.z = f2bf(xv[j].z); bv.w = f2bf(xv[j].w);
            int uidx = (row * 256 + c4) ^ ((row & 7) << 3);
            *reinterpret_cast<ushort4*>(&xs[uidx]) = bv;
        }
#pragma unroll
        for (int j = 0; j < 2; j++) {
            int f = j * 512 + tid;
            int row = f >> 4, c4 = (f & 15) * 4;
            ushort4 bv;
            bv.x = f2bf((float)av[j].x); bv.y = f2bf((float)av[j].y);
            bv.z = f2bf((float)av[j].z); bv.w = f2bf((float)av[j].w);
            int uidx = (row * 64 + c4) ^ ((row & 7) << 3);
            *reinterpret_cast<ushort4*>(&as[uidx]) = bv;
        }
    }
    __syncthreads();

    // ---- phase 1: h cols [w*32, w*32+32), M=64, K=256; 2-deep pipelined ----
    int wc0 = w * 32;
    floatx4 acc1[4][2];
#pragma unroll
    for (int mt = 0; mt < 4; mt++)
#pragma unroll
        for (int nt = 0; nt < 2; nt++) acc1[mt][nt] = (floatx4){0.f, 0.f, 0.f, 0.f};
    float b1v[2];
#pragma unroll
    for (int nt = 0; nt < 2; nt++) b1v[nt] = b1[wc0 + nt * 16 + lrow];

    bhalf8 af[2][4], bf[2][2];
#define LOAD_P1(buf, KS)                                                              \
    {                                                                                 \
        int koff = (KS) * 32 + lkb * 8;                                               \
        _Pragma("unroll")                                                             \
        for (int mt = 0; mt < 4; mt++) {                                              \
            int row = mt * 16 + lrow;                                                 \
            int uidx = (row * 256 + koff) ^ ((row & 7) << 3);                         \
            af[buf][mt] = *reinterpret_cast<const bhalf8*>(&xs[uidx]);                \
        }                                                                             \
        _Pragma("unroll")                                                             \
        for (int nt = 0; nt < 2; nt++) {                                              \
            int col = wc0 + nt * 16 + lrow;                                           \
            bf[buf][nt] = *reinterpret_cast<const bhalf8*>(&W1T[(size_t)col * 256 + koff]); \
        }                                                                             \
    }
    LOAD_P1(0, 0)
#pragma unroll
    for (int ks = 0; ks < 8; ks++) {
        int cur = ks & 1;
        if (ks < 7) {
            int nxt = cur ^ 1;
            if ((ks & 1) == 0) LOAD_P1(1, ks + 1) else LOAD_P1(0, ks + 1)
            (void)nxt;
        }
#pragma unroll
        for (int mt = 0; mt < 4; mt++)
#pragma unroll
            for (int nt = 0; nt < 2; nt++)
                acc1[mt][nt] = __builtin_amdgcn_mfma_f32_16x16x32_bf16(
                    (cur == 0) ? af[0][mt] : af[1][mt],
                    (cur == 0) ? bf[0][nt] : bf[1][nt],
                    acc1[mt][nt], 0, 0, 0);
    }
#undef LOAD_P1
    __syncthreads();   // all xs reads done before overwrite

    // ---- write z tile (bf16(relu(h+b1))) into xs region ----
#pragma unroll
    for (int mt = 0; mt < 4; mt++)
#pragma unroll
        for (int nt = 0; nt < 2; nt++) {
            int col = wc0 + nt * 16 + lrow;
#pragma unroll
            for (int r = 0; r < 4; r++) {
                int row = mt * 16 + lkb * 4 + r;
                float v = fmaxf(acc1[mt][nt][r] + b1v[nt], 0.f);
                int uidx = (row * 256 + col) ^ ((row & 7) << 3);
                xs[uidx] = f2bf(v);
            }
        }
    __syncthreads();

    // ---- phase 2: wave pair g=w>>1 owns rows [g*16,+16); even wave nt={0,1}, odd nt={2} ----
    int r0 = (w >> 1) * 16;
    int odd = w & 1;
    floatx4 acc2[2];
    acc2[0] = (floatx4){0.f, 0.f, 0.f, 0.f};
    acc2[1] = (floatx4){0.f, 0.f, 0.f, 0.f};
    int c0 = odd ? 32 : 0;                  // first output-col tile this wave computes
    {
        bhalf8 pa[2], pb0[2], pb1[2];
#define LOAD_P2(buf, KS)                                                                   \
        {                                                                                  \
            int koff = (KS) * 32 + lkb * 8;                                                \
            int row = r0 + lrow;                                                           \
            int uidx = (row * 256 + koff) ^ ((row & 7) << 3);                              \
            pa[buf] = *reinterpret_cast<const bhalf8*>(&xs[uidx]);                         \
            pb0[buf] = *reinterpret_cast<const bhalf8*>(&W2T[(size_t)(c0 + lrow) * 320 + koff]); \
            pb1[buf] = *reinterpret_cast<const bhalf8*>(&W2T[(size_t)(16 + lrow) * 320 + koff]); \
        }
        LOAD_P2(0, 0)
#pragma unroll
        for (int ks = 0; ks < 8; ks++) {
            int cur = ks & 1;
            if (ks < 7) {
                if ((ks & 1) == 0) LOAD_P2(1, ks + 1) else LOAD_P2(0, ks + 1)
            }
            bhalf8 a  = (cur == 0) ? pa[0] : pa[1];
            bhalf8 b0 = (cur == 0) ? pb0[0] : pb0[1];
            acc2[0] = __builtin_amdgcn_mfma_f32_16x16x32_bf16(a, b0, acc2[0], 0, 0, 0);
            if (!odd) {
                bhalf8 b1f = (cur == 0) ? pb1[0] : pb1[1];
                acc2[1] = __builtin_amdgcn_mfma_f32_16x16x32_bf16(a, b1f, acc2[1], 0, 0, 0);
            }
        }
#undef LOAD_P2
    }
#pragma unroll
    for (int ks = 0; ks < 2; ks++) {
        int koff = ks * 32 + lkb * 8;
        int row = r0 + lrow;
        int uidx = (row * 64 + koff) ^ ((row & 7) << 3);
        bhalf8 a = *reinterpret_cast<const bhalf8*>(&as[uidx]);
        bhalf8 b0 = *reinterpret_cast<const bhalf8*>(&W2T[(size_t)(c0 + lrow) * 320 + 256 + koff]);
        acc2[0] = __builtin_amdgcn_mfma_f32_16x16x32_bf16(a, b0, acc2[0], 0, 0, 0);
        if (!odd) {
            bhalf8 b1f = *reinterpret_cast<const bhalf8*>(&W2T[(size_t)(16 + lrow) * 320 + 256 + koff]);
            acc2[1] = __builtin_amdgcn_mfma_f32_16x16x32_bf16(a, b1f, acc2[1], 0, 0, 0);
        }
    }
    // ---- epilogue: + b2, store ----
    int ntend = odd ? 1 : 2;
#pragma unroll
    for (int nt = 0; nt < 2; nt++) {
        if (nt >= ntend) continue;
        int col = c0 + nt * 16 + lrow;
        if (col >= 40) continue;
        float bb = b2[col];
#pragma unroll
        for (int r = 0; r < 4; r++) {
            int row = n0 + r0 + lkb * 4 + r;
            if (row < N) out[(size_t)row * 40 + col] = acc2[nt][r] + bb;
        }
    }
}

extern "C" void kernel_launch(void* const* d_in, const int* in_sizes, int n_in,
                              void* d_out, int out_size, void* d_ws, size_t ws_size,
                              hipStream_t stream) {
    const float* x  = (const float*)d_in[0];
    const int*   ei = (const int*)d_in[1];
    const int*   ef = (const int*)d_in[2];
    const float* W1 = (const float*)d_in[3];
    const float* b1 = (const float*)d_in[4];
    const float* W2 = (const float*)d_in[5];
    const float* b2 = (const float*)d_in[6];
    float* out = (float*)d_out;

    const int HID = in_sizes[4];            // 256
    const int D   = in_sizes[3] / HID;      // 256
    const int N   = in_sizes[0] / D;        // 100000
    const int E   = in_sizes[1] / 2;        // 3200000
    (void)HID; (void)D;

    const int nblk_e = (E + 4096 - 1) / 4096;       // 782
    const int nbuck  = (N + BROWS - 1) / BROWS;     // 782

    // workspace layout, 4-byte units (d_ws 16B-aligned); total ~66MB
    int* ws = (int*)d_ws;
    size_t o = 0;
    unsigned short* agg = (unsigned short*)(ws + o); o += (size_t)N * 32;      // N*64 u16
    int* pos = ws + o;                               o += N;
    int* rank = ws + o;                              o += N;
    int* cursorb = ws + o;                           o += nbuck;
    int* bsum_e = ws + o;                            o += nblk_e + 1;
    o = (o + 3) & ~(size_t)3;                        // 16B align
    unsigned* binned = (unsigned*)(ws + o);          o += (size_t)nbuck * BCAP;  // u32 entries
    unsigned short* W1T = (unsigned short*)(ws + o); o += 32768;   // 256x256 bf16
    unsigned short* W2T = (unsigned short*)(ws + o); o += 7680;    // 48x320 bf16

    hipLaunchKernelGGL(k_prep, dim3(256), dim3(256), 0, stream, W1, W2, W1T, W2T);
    hipLaunchKernelGGL(k_init, dim3((N + 255) / 256), dim3(256), 0, stream, pos, cursorb, N, nbuck, E);
    hipLaunchKernelGGL(k_posmin, dim3((E + 255) / 256), dim3(256), 0, stream, ei, pos, E);
    hipLaunchKernelGGL(k_flagsum, dim3(nblk_e), dim3(256), 0, stream, ei, pos, bsum_e, E);
    hipLaunchKernelGGL(k_scanbsum, dim3(1), dim3(1024), 0, stream, bsum_e, nblk_e);
    hipLaunchKernelGGL(k_prefix_rank, dim3(nblk_e), dim3(256), 0, stream, ei, pos, bsum_e, rank, E);
    hipLaunchKernelGGL(k_bin, dim3((E + EPB - 1) / EPB), dim3(TPB_BIN), 0, stream,
                       ei, rank, ef, cursorb, binned, E, nbuck);
    hipLaunchKernelGGL(k_bgather, dim3(nbuck), dim3(256), 0, stream, cursorb, binned, agg, N);
    hipLaunchKernelGGL(k_fused, dim3((N + 63) / 64), dim3(512), 0, stream,
                       x, W1T, b1, W2T, b2, agg, out, N);
}